// Round 12
// baseline (398.359 us; speedup 1.0000x reference)
//
#include <hip/hip_runtime.h>
#include <math.h>

typedef float f4 __attribute__((ext_vector_type(4)));
typedef float f32x4 __attribute__((ext_vector_type(4)));
typedef short s8 __attribute__((ext_vector_type(8)));  // 8 bf16 (4 VGPRs)

static constexpr int N = 50000;
static constexpr int E = 800000;
static constexpr int D = 128;
static constexpr int SCAN_NB = (N + 255) / 256;        // 196
static constexpr int MBLK = 128;                       // rows per layer-block
static constexpr int GRID_M = (N + MBLK - 1) / MBLK;   // 391
static constexpr int N_PAD = GRID_M * MBLK;            // 50048
static constexpr int WT_PITCH = 136;                   // LDS pad

__device__ inline unsigned short f32_bf16_rne(float x) {
    unsigned u = __float_as_uint(x);
    return (unsigned short)((u + 0x7FFF + ((u >> 16) & 1)) >> 16);
}
__device__ inline float bf16_f32(unsigned short h) {
    return __uint_as_float((unsigned)h << 16);
}

// --- int degree histogram ---
__global__ void deg_kernel(const int* __restrict__ src, const int* __restrict__ dst,
                           int* __restrict__ deg_out, int* __restrict__ deg_in) {
    int e = blockIdx.x * 256 + threadIdx.x;
    if (e < E) {
        atomicAdd(&deg_out[src[e]], 1);
        atomicAdd(&deg_in[dst[e]], 1);
    }
}

// --- scan pass 1 (+ fused norms): per-block sums of deg_in ---
__global__ __launch_bounds__(256) void scan_bsum_norm_kernel(
    const int* __restrict__ deg_out, const int* __restrict__ deg_in,
    float* __restrict__ norm_src, float* __restrict__ norm_dst,
    int* __restrict__ bsums) {
    int i = blockIdx.x * 256 + threadIdx.x;
    int v = 0;
    if (i < N) {
        norm_src[i] = rsqrtf(fmaxf((float)deg_out[i], 1.0f));
        norm_dst[i] = rsqrtf(fmaxf((float)deg_in[i], 1.0f));
        v = deg_in[i];
    }
#pragma unroll
    for (int off = 1; off < 64; off <<= 1) v += __shfl_xor(v, off, 64);
    __shared__ int ws[4];
    if ((threadIdx.x & 63) == 0) ws[threadIdx.x >> 6] = v;
    __syncthreads();
    if (threadIdx.x == 0) bsums[blockIdx.x] = ws[0] + ws[1] + ws[2] + ws[3];
}

// --- scan pass 2: exclusive scan of block sums (1 block) ---
__global__ __launch_bounds__(256) void scan_bsums_kernel(int* __restrict__ bsums) {
    __shared__ int s[256];
    int t = threadIdx.x;
    s[t] = (t < SCAN_NB) ? bsums[t] : 0;
    __syncthreads();
    for (int off = 1; off < 256; off <<= 1) {
        int v = (t >= off) ? s[t - off] : 0;
        __syncthreads();
        s[t] += v;
        __syncthreads();
    }
    if (t < SCAN_NB) bsums[t] = (t == 0) ? 0 : s[t - 1];
}

// --- scan pass 3: rescan + block offset -> row_ptr ---
__global__ __launch_bounds__(256) void scan_final_kernel(const int* __restrict__ deg,
                                                         const int* __restrict__ bsums,
                                                         int* __restrict__ row_ptr) {
    __shared__ int s[256];
    int b = blockIdx.x, t = threadIdx.x;
    int i = b * 256 + t;
    s[t] = (i < N) ? deg[i] : 0;
    __syncthreads();
    for (int off = 1; off < 256; off <<= 1) {
        int v = (t >= off) ? s[t - off] : 0;
        __syncthreads();
        s[t] += v;
        __syncthreads();
    }
    if (i < N) row_ptr[i + 1] = s[t] + bsums[b];
    if (i == 0) row_ptr[0] = 0;
}

// --- csr fill ---
__global__ void fill_kernel(const int* __restrict__ src, const int* __restrict__ dst,
                            const int* __restrict__ row_ptr, int* __restrict__ cursor,
                            int* __restrict__ csr_src) {
    int e = blockIdx.x * 256 + threadIdx.x;
    if (e < E) {
        int d = dst[e];
        int pos = row_ptr[d] + atomicAdd(&cursor[d], 1);
        csr_src[pos] = src[e];
    }
}

// --- hs[i] = emb[batch[i]] * norm_src[i] ---
__global__ void gather_kernel(const int* __restrict__ batch, const float* __restrict__ emb,
                              const float* __restrict__ norm_src, float* __restrict__ hs) {
    int gid = blockIdx.x * 256 + threadIdx.x;
    int i = gid >> 5;
    int c = (gid & 31) << 2;
    if (i < N) {
        float s = norm_src[i];
        f4 v = *(const f4*)(emb + (size_t)batch[i] * D + c);
        *(f4*)(hs + (size_t)i * D + c) = v * s;
    }
}

// --- W prep: wt[layer][hi/lo][n][k] = bf16 split of W[k][n] (transposed) ---
__global__ void wprep_kernel(const float* __restrict__ W1, const float* __restrict__ W2,
                             const float* __restrict__ W3, short* __restrict__ wt) {
    int idx = blockIdx.x * 256 + threadIdx.x;
    if (idx >= 3 * D * D) return;
    int l = idx >> 14;
    int e = idx & (D * D - 1);
    int n = e >> 7, k = e & 127;
    const float* W = (l == 0) ? W1 : ((l == 1) ? W2 : W3);
    float w = W[(size_t)k * D + n];
    unsigned short h = f32_bf16_rne(w);
    unsigned short lo = f32_bf16_rne(w - bf16_f32(h));
    wt[(size_t)l * 2 * D * D + (size_t)n * D + k] = (short)h;
    wt[(size_t)l * 2 * D * D + D * D + (size_t)n * D + k] = (short)lo;
}

// --- FUSED layer: aggregate (gather-sum in MFMA-fragment layout) + GEMM + epilogue.
// Block: 512 thr = 8 waves, 128 rows (wave wv owns rows wv*16..+16).
// Lane l of wave: A-frag row = l&15 (node = blk*128 + wv*16 + (l&15));
// lane accumulates cols {kt*32 + (l>>4)*8 + i} (32 fp32) directly in registers —
// gathered aggregate lands exactly in MFMA A-fragment layout, zero cross-lane.
// Then split to bf16 hi/lo, 3-term MFMA vs W (hi/lo in LDS), fused epilogue.
__global__ __launch_bounds__(512, 4) void layer_kernel(
    const int* __restrict__ row_ptr, const int* __restrict__ csr_src,
    const float* __restrict__ hs_in, const short* __restrict__ wth,
    const float* __restrict__ bias, const float* __restrict__ norm_dst,
    const float* __restrict__ post, float* __restrict__ out) {
    __shared__ short wt_h[D * WT_PITCH];   // 34816 B
    __shared__ short wt_l[D * WT_PITCH];   // 34816 B

    int tid = threadIdx.x;
    const short* gh = wth;
    const short* gl = wth + (size_t)D * D;
#pragma unroll
    for (int it = 0; it < 4; ++it) {
        int c = tid + it * 512;            // 2048 chunks of 8 shorts
        int n = c >> 4, kc = c & 15;
        *(s8*)(&wt_h[n * WT_PITCH + kc * 8]) = *(const s8*)(gh + (size_t)n * D + kc * 8);
        *(s8*)(&wt_l[n * WT_PITCH + kc * 8]) = *(const s8*)(gl + (size_t)n * D + kc * 8);
    }

    int wv = tid >> 6;
    int lane = tid & 63;
    int lg = lane >> 4;                    // k-slice group 0..3
    int lr = lane & 15;                    // A-frag row within 16-tile
    int node = blockIdx.x * MBLK + wv * 16 + lr;
    int cbase = lg * 8;

    // --- gather-aggregate phase (no LDS dependency; overlaps W staging) ---
    f4 ga[8];                              // 32 fp32: ga[2*kt], ga[2*kt+1]
#pragma unroll
    for (int j = 0; j < 8; ++j) ga[j] = (f4)0.0f;

    if (node < N) {
        int beg = row_ptr[node], end = row_ptr[node + 1];
        int e = beg;
        for (; e + 1 < end; e += 2) {
            const float* p0 = hs_in + (size_t)csr_src[e] * D + cbase;
            const float* p1 = hs_in + (size_t)csr_src[e + 1] * D + cbase;
            f4 v0 = *(const f4*)(p0);
            f4 v1 = *(const f4*)(p0 + 4);
            f4 v2 = *(const f4*)(p0 + 32);
            f4 v3 = *(const f4*)(p0 + 36);
            f4 v4 = *(const f4*)(p0 + 64);
            f4 v5 = *(const f4*)(p0 + 68);
            f4 v6 = *(const f4*)(p0 + 96);
            f4 v7 = *(const f4*)(p0 + 100);
            f4 u0 = *(const f4*)(p1);
            f4 u1 = *(const f4*)(p1 + 4);
            f4 u2 = *(const f4*)(p1 + 32);
            f4 u3 = *(const f4*)(p1 + 36);
            f4 u4 = *(const f4*)(p1 + 64);
            f4 u5 = *(const f4*)(p1 + 68);
            f4 u6 = *(const f4*)(p1 + 96);
            f4 u7 = *(const f4*)(p1 + 100);
            ga[0] += v0; ga[1] += v1; ga[2] += v2; ga[3] += v3;
            ga[4] += v4; ga[5] += v5; ga[6] += v6; ga[7] += v7;
            ga[0] += u0; ga[1] += u1; ga[2] += u2; ga[3] += u3;
            ga[4] += u4; ga[5] += u5; ga[6] += u6; ga[7] += u7;
        }
        if (e < end) {
            const float* p0 = hs_in + (size_t)csr_src[e] * D + cbase;
            ga[0] += *(const f4*)(p0);
            ga[1] += *(const f4*)(p0 + 4);
            ga[2] += *(const f4*)(p0 + 32);
            ga[3] += *(const f4*)(p0 + 36);
            ga[4] += *(const f4*)(p0 + 64);
            ga[5] += *(const f4*)(p0 + 68);
            ga[6] += *(const f4*)(p0 + 96);
            ga[7] += *(const f4*)(p0 + 100);
        }
    }

    // --- split to bf16 hi/lo fragments (already in A-frag layout) ---
    s8 ah[4], al[4];
#pragma unroll
    for (int kt = 0; kt < 4; ++kt) {
#pragma unroll
        for (int i = 0; i < 8; ++i) {
            float x = (i < 4) ? ga[2 * kt][i] : ga[2 * kt + 1][i - 4];
            unsigned short h = f32_bf16_rne(x);
            ah[kt][i] = (short)h;
            al[kt][i] = (short)f32_bf16_rne(x - bf16_f32(h));
        }
    }

    __syncthreads();   // W staged

    f32x4 acc[8];
#pragma unroll
    for (int nt = 0; nt < 8; ++nt) acc[nt] = (f32x4)0.0f;

#pragma unroll
    for (int kt = 0; kt < 4; ++kt) {
        int ko = kt * 32 + cbase;
#pragma unroll
        for (int nt = 0; nt < 8; ++nt) {
            int bidx = (nt * 16 + lr) * WT_PITCH + ko;
            s8 bh = *(const s8*)(&wt_h[bidx]);
            s8 bl = *(const s8*)(&wt_l[bidx]);
            acc[nt] = __builtin_amdgcn_mfma_f32_16x16x32_bf16(ah[kt], bh, acc[nt], 0, 0, 0);
            acc[nt] = __builtin_amdgcn_mfma_f32_16x16x32_bf16(al[kt], bh, acc[nt], 0, 0, 0);
            acc[nt] = __builtin_amdgcn_mfma_f32_16x16x32_bf16(ah[kt], bl, acc[nt], 0, 0, 0);
        }
    }

    // --- epilogue: C[row = wv*16 + lg*4 + i][col = nt*16 + lr] ---
    int r0 = blockIdx.x * MBLK + wv * 16 + lg * 4;
    float nd[4], ps[4];
#pragma unroll
    for (int i = 0; i < 4; ++i) {
        int gr = r0 + i;
        nd[i] = (gr < N) ? norm_dst[gr] : 0.0f;
        ps[i] = (gr < N) ? (post ? post[gr] : 1.0f) : 0.0f;
    }
#pragma unroll
    for (int nt = 0; nt < 8; ++nt) {
        int col = nt * 16 + lr;
        float bv = bias[col];
#pragma unroll
        for (int i = 0; i < 4; ++i) {
            int gr = r0 + i;
            if (gr < N) {
                float v = fmaxf(acc[nt][i] * nd[i] + bv, 0.0f) * ps[i];
                out[(size_t)gr * D + col] = v;
            }
        }
    }
}

extern "C" void kernel_launch(void* const* d_in, const int* in_sizes, int n_in,
                              void* d_out, int out_size, void* d_ws, size_t ws_size,
                              hipStream_t stream) {
    const int*   batch = (const int*)d_in[0];
    const int*   src   = (const int*)d_in[1];
    const int*   dst   = (const int*)d_in[2];
    const float* emb   = (const float*)d_in[3];
    const float* W1    = (const float*)d_in[4];
    const float* b1    = (const float*)d_in[5];
    const float* W2    = (const float*)d_in[6];
    const float* b2    = (const float*)d_in[7];
    const float* W3    = (const float*)d_in[8];
    const float* b3    = (const float*)d_in[9];
    float* out = (float*)d_out;

    // ws layout (4B elems): norm_src[N] | norm_dst[N] | row_ptr[N+1] | csr_src[E]
    //                       | hs_a[N_PAD*D] | hs_b[N_PAD*D] | wt (3*2*D*D shorts)
    // Double-buffered hs: fused layers read one buffer, write the other.
    // Transients (deg_out, deg_in, cursor, bsums) alias hs_a: last read by fill,
    // before gather_kernel writes hs_a.
    float* norm_src = (float*)d_ws;
    float* norm_dst = norm_src + N;
    int*   row_ptr  = (int*)(norm_dst + N);
    int*   csr_src  = row_ptr + (N + 1);
    float* hs_a     = (float*)(csr_src + E) + 3;  // 16B alignment
    float* hs_b     = hs_a + (size_t)N_PAD * D;
    short* wt       = (short*)(hs_b + (size_t)N_PAD * D);
    int*   deg_out  = (int*)hs_a;     // transient
    int*   deg_in   = deg_out + N;
    int*   cursor   = deg_in + N;
    int*   bsums    = cursor + N;

    hipMemsetAsync(deg_out, 0, 3 * (size_t)N * sizeof(int), stream);
    deg_kernel<<<(E + 255) / 256, 256, 0, stream>>>(src, dst, deg_out, deg_in);
    scan_bsum_norm_kernel<<<SCAN_NB, 256, 0, stream>>>(deg_out, deg_in,
                                                       norm_src, norm_dst, bsums);
    scan_bsums_kernel<<<1, 256, 0, stream>>>(bsums);
    scan_final_kernel<<<SCAN_NB, 256, 0, stream>>>(deg_in, bsums, row_ptr);
    fill_kernel<<<(E + 255) / 256, 256, 0, stream>>>(src, dst, row_ptr, cursor,
                                                     csr_src);
    gather_kernel<<<((size_t)N * 32 + 255) / 256, 256, 0, stream>>>(batch, emb,
                                                                    norm_src, hs_a);
    wprep_kernel<<<(3 * D * D + 255) / 256, 256, 0, stream>>>(W1, W2, W3, wt);

    const float* bs[3] = {b1, b2, b3};
    // l=0: hs_a -> hs_b ; l=1: hs_b -> hs_a ; l=2: hs_a -> out
    layer_kernel<<<GRID_M, 512, 0, stream>>>(row_ptr, csr_src, hs_a, wt,
                                             bs[0], norm_dst, norm_src, hs_b);
    layer_kernel<<<GRID_M, 512, 0, stream>>>(row_ptr, csr_src, hs_b,
                                             wt + (size_t)2 * D * D,
                                             bs[1], norm_dst, norm_src, hs_a);
    layer_kernel<<<GRID_M, 512, 0, stream>>>(row_ptr, csr_src, hs_a,
                                             wt + (size_t)4 * D * D,
                                             bs[2], norm_dst, nullptr, out);
}

// Round 13
// 380.177 us; speedup vs baseline: 1.0478x; 1.0478x over previous
//
#include <hip/hip_runtime.h>
#include <math.h>

typedef float f4 __attribute__((ext_vector_type(4)));
typedef float f32x4 __attribute__((ext_vector_type(4)));
typedef short s8 __attribute__((ext_vector_type(8)));  // 8 bf16 (4 VGPRs)
typedef short s4 __attribute__((ext_vector_type(4)));  // 4 bf16 (2 VGPRs)

static constexpr int N = 50000;
static constexpr int E = 800000;
static constexpr int D = 128;
static constexpr int SCAN_NB = (N + 255) / 256;        // 196
static constexpr int MBLK = 128;                       // gemm rows/block
static constexpr int GRID_M = (N + MBLK - 1) / MBLK;   // 391
static constexpr int N_PAD = GRID_M * MBLK;            // 50048
static constexpr int WT_PITCH = 136;                   // LDS pad

__device__ inline unsigned short f32_bf16_rne(float x) {
    unsigned u = __float_as_uint(x);
    return (unsigned short)((u + 0x7FFF + ((u >> 16) & 1)) >> 16);
}
__device__ inline float bf16_f32(unsigned short h) {
    return __uint_as_float((unsigned)h << 16);
}

// --- int degree histogram ---
__global__ void deg_kernel(const int* __restrict__ src, const int* __restrict__ dst,
                           int* __restrict__ deg_out, int* __restrict__ deg_in) {
    int e = blockIdx.x * 256 + threadIdx.x;
    if (e < E) {
        atomicAdd(&deg_out[src[e]], 1);
        atomicAdd(&deg_in[dst[e]], 1);
    }
}

// --- scan pass 1 (+ fused norms): per-block sums of deg_in ---
__global__ __launch_bounds__(256) void scan_bsum_norm_kernel(
    const int* __restrict__ deg_out, const int* __restrict__ deg_in,
    float* __restrict__ norm_src, float* __restrict__ norm_dst,
    int* __restrict__ bsums) {
    int i = blockIdx.x * 256 + threadIdx.x;
    int v = 0;
    if (i < N) {
        norm_src[i] = rsqrtf(fmaxf((float)deg_out[i], 1.0f));
        norm_dst[i] = rsqrtf(fmaxf((float)deg_in[i], 1.0f));
        v = deg_in[i];
    }
#pragma unroll
    for (int off = 1; off < 64; off <<= 1) v += __shfl_xor(v, off, 64);
    __shared__ int ws[4];
    if ((threadIdx.x & 63) == 0) ws[threadIdx.x >> 6] = v;
    __syncthreads();
    if (threadIdx.x == 0) bsums[blockIdx.x] = ws[0] + ws[1] + ws[2] + ws[3];
}

// --- scan pass 2: exclusive scan of block sums (1 block) ---
__global__ __launch_bounds__(256) void scan_bsums_kernel(int* __restrict__ bsums) {
    __shared__ int s[256];
    int t = threadIdx.x;
    s[t] = (t < SCAN_NB) ? bsums[t] : 0;
    __syncthreads();
    for (int off = 1; off < 256; off <<= 1) {
        int v = (t >= off) ? s[t - off] : 0;
        __syncthreads();
        s[t] += v;
        __syncthreads();
    }
    if (t < SCAN_NB) bsums[t] = (t == 0) ? 0 : s[t - 1];
}

// --- scan pass 3: rescan + block offset -> row_ptr ---
__global__ __launch_bounds__(256) void scan_final_kernel(const int* __restrict__ deg,
                                                         const int* __restrict__ bsums,
                                                         int* __restrict__ row_ptr) {
    __shared__ int s[256];
    int b = blockIdx.x, t = threadIdx.x;
    int i = b * 256 + t;
    s[t] = (i < N) ? deg[i] : 0;
    __syncthreads();
    for (int off = 1; off < 256; off <<= 1) {
        int v = (t >= off) ? s[t - off] : 0;
        __syncthreads();
        s[t] += v;
        __syncthreads();
    }
    if (i < N) row_ptr[i + 1] = s[t] + bsums[b];
    if (i == 0) row_ptr[0] = 0;
}

// --- csr fill ---
__global__ void fill_kernel(const int* __restrict__ src, const int* __restrict__ dst,
                            const int* __restrict__ row_ptr, int* __restrict__ cursor,
                            int* __restrict__ csr_src) {
    int e = blockIdx.x * 256 + threadIdx.x;
    if (e < E) {
        int d = dst[e];
        int pos = row_ptr[d] + atomicAdd(&cursor[d], 1);
        csr_src[pos] = src[e];
    }
}

// --- hs[i] = emb[batch[i]] * norm_src[i] ---
__global__ void gather_kernel(const int* __restrict__ batch, const float* __restrict__ emb,
                              const float* __restrict__ norm_src, float* __restrict__ hs) {
    int gid = blockIdx.x * 256 + threadIdx.x;
    int i = gid >> 5;
    int c = (gid & 31) << 2;
    if (i < N) {
        float s = norm_src[i];
        f4 v = *(const f4*)(emb + (size_t)batch[i] * D + c);
        *(f4*)(hs + (size_t)i * D + c) = v * s;
    }
}

// --- agg: 1 wave/node, 2 edge-groups x 8-deep; full row; bf16 hi/lo out ---
// (R8 champion: 66.4 µs, FETCH = 213 MB compulsory = 8 XCD x 25.6 MB table.)
__global__ void agg_kernel(const int* __restrict__ row_ptr, const int* __restrict__ csr_src,
                           const float* __restrict__ hs,
                           short* __restrict__ agg_h, short* __restrict__ agg_l) {
    int gid = blockIdx.x * 256 + threadIdx.x;
    int node = gid >> 6;
    if (node >= N) return;
    int lane = threadIdx.x & 63;
    int grp = lane >> 5;
    int col = (lane & 31) << 2;
    int beg = row_ptr[node], end = row_ptr[node + 1];

    f4 a0 = (f4)0.0f, a1 = (f4)0.0f, a2 = (f4)0.0f, a3 = (f4)0.0f;
    f4 a4 = (f4)0.0f, a5 = (f4)0.0f, a6 = (f4)0.0f, a7 = (f4)0.0f;
    int e = beg + grp;
    for (; e + 14 < end; e += 16) {
        int s0 = csr_src[e];
        int s1 = csr_src[e + 2];
        int s2 = csr_src[e + 4];
        int s3 = csr_src[e + 6];
        int s4 = csr_src[e + 8];
        int s5 = csr_src[e + 10];
        int s6 = csr_src[e + 12];
        int s7 = csr_src[e + 14];
        a0 += *(const f4*)(hs + (size_t)s0 * D + col);
        a1 += *(const f4*)(hs + (size_t)s1 * D + col);
        a2 += *(const f4*)(hs + (size_t)s2 * D + col);
        a3 += *(const f4*)(hs + (size_t)s3 * D + col);
        a4 += *(const f4*)(hs + (size_t)s4 * D + col);
        a5 += *(const f4*)(hs + (size_t)s5 * D + col);
        a6 += *(const f4*)(hs + (size_t)s6 * D + col);
        a7 += *(const f4*)(hs + (size_t)s7 * D + col);
    }
    for (; e < end; e += 2)
        a0 += *(const f4*)(hs + (size_t)csr_src[e] * D + col);
    a0 += a1; a2 += a3; a4 += a5; a6 += a7;
    a0 += a2; a4 += a6;
    a0 += a4;

    f4 o;
#pragma unroll
    for (int j = 0; j < 4; ++j)
        o[j] = a0[j] + __shfl_xor(a0[j], 32, 64);
    if (grp == 0) {
        s4 oh, ol;
#pragma unroll
        for (int j = 0; j < 4; ++j) {
            unsigned short h = f32_bf16_rne(o[j]);
            oh[j] = (short)h;
            ol[j] = (short)f32_bf16_rne(o[j] - bf16_f32(h));
        }
        *(s4*)(agg_h + (size_t)node * D + col) = oh;
        *(s4*)(agg_l + (size_t)node * D + col) = ol;
    }
}

// --- W prep: wt[layer][hi/lo][n][k] = bf16 split of W[k][n] (transposed) ---
__global__ void wprep_kernel(const float* __restrict__ W1, const float* __restrict__ W2,
                             const float* __restrict__ W3, short* __restrict__ wt) {
    int idx = blockIdx.x * 256 + threadIdx.x;
    if (idx >= 3 * D * D) return;
    int l = idx >> 14;
    int e = idx & (D * D - 1);
    int n = e >> 7, k = e & 127;
    const float* W = (l == 0) ? W1 : ((l == 1) ? W2 : W3);
    float w = W[(size_t)k * D + n];
    unsigned short h = f32_bf16_rne(w);
    unsigned short lo = f32_bf16_rne(w - bf16_f32(h));
    wt[(size_t)l * 2 * D * D + (size_t)n * D + k] = (short)h;
    wt[(size_t)l * 2 * D * D + D * D + (size_t)n * D + k] = (short)lo;
}

// --- MFMA GEMM: 128 rows x 128 cols per block; 512 thr = 8 waves.
// grid=391 < 512 resident capacity (2 blk/CU) -> single occupancy round.
// 3-term bf16 split: C = Ah@Wh + Al@Wh + Ah@Wl.
__global__ __launch_bounds__(512, 2) void gemm_mfma_kernel(
    const short* __restrict__ Ah, const short* __restrict__ Al,
    const short* __restrict__ wth,
    const float* __restrict__ bias, const float* __restrict__ norm_dst,
    const float* __restrict__ post, float* __restrict__ out) {
    __shared__ short wt_h[D * WT_PITCH];   // 34816 B
    __shared__ short wt_l[D * WT_PITCH];   // 34816 B

    int tid = threadIdx.x;
    const short* gh = wth;
    const short* gl = wth + (size_t)D * D;

#pragma unroll
    for (int it = 0; it < 4; ++it) {
        int c = tid + it * 512;            // 2048 chunks of 8 shorts
        int n = c >> 4, kc = c & 15;
        *(s8*)(&wt_h[n * WT_PITCH + kc * 8]) = *(const s8*)(gh + (size_t)n * D + kc * 8);
        *(s8*)(&wt_l[n * WT_PITCH + kc * 8]) = *(const s8*)(gl + (size_t)n * D + kc * 8);
    }
    __syncthreads();

    int wv = tid >> 6;                     // 0..7
    int lane = tid & 63;
    int lg = lane >> 4;
    int lr = lane & 15;

    int arow = blockIdx.x * MBLK + wv * 16 + lr;
    const short* ahp = Ah + (size_t)arow * D;
    const short* alp = Al + (size_t)arow * D;

    f32x4 acc[8];
#pragma unroll
    for (int nt = 0; nt < 8; ++nt) acc[nt] = (f32x4)0.0f;

#pragma unroll
    for (int kt = 0; kt < 4; ++kt) {
        int ko = kt * 32 + lg * 8;
        s8 ah = *(const s8*)(ahp + ko);
        s8 al = *(const s8*)(alp + ko);
#pragma unroll
        for (int nt = 0; nt < 8; ++nt) {
            int bidx = (nt * 16 + lr) * WT_PITCH + ko;
            s8 bh = *(const s8*)(&wt_h[bidx]);
            s8 bl = *(const s8*)(&wt_l[bidx]);
            acc[nt] = __builtin_amdgcn_mfma_f32_16x16x32_bf16(ah, bh, acc[nt], 0, 0, 0);
            acc[nt] = __builtin_amdgcn_mfma_f32_16x16x32_bf16(al, bh, acc[nt], 0, 0, 0);
            acc[nt] = __builtin_amdgcn_mfma_f32_16x16x32_bf16(ah, bl, acc[nt], 0, 0, 0);
        }
    }

    int r0 = blockIdx.x * MBLK + wv * 16 + lg * 4;
    float nd[4], ps[4];
#pragma unroll
    for (int i = 0; i < 4; ++i) {
        int gr = r0 + i;
        nd[i] = (gr < N) ? norm_dst[gr] : 0.0f;
        ps[i] = (gr < N) ? (post ? post[gr] : 1.0f) : 0.0f;
    }
#pragma unroll
    for (int nt = 0; nt < 8; ++nt) {
        int col = nt * 16 + lr;
        float bv = bias[col];
#pragma unroll
        for (int i = 0; i < 4; ++i) {
            int gr = r0 + i;
            if (gr < N) {
                float v = fmaxf(acc[nt][i] * nd[i] + bv, 0.0f) * ps[i];
                out[(size_t)gr * D + col] = v;
            }
        }
    }
}

extern "C" void kernel_launch(void* const* d_in, const int* in_sizes, int n_in,
                              void* d_out, int out_size, void* d_ws, size_t ws_size,
                              hipStream_t stream) {
    const int*   batch = (const int*)d_in[0];
    const int*   src   = (const int*)d_in[1];
    const int*   dst   = (const int*)d_in[2];
    const float* emb   = (const float*)d_in[3];
    const float* W1    = (const float*)d_in[4];
    const float* b1    = (const float*)d_in[5];
    const float* W2    = (const float*)d_in[6];
    const float* b2    = (const float*)d_in[7];
    const float* W3    = (const float*)d_in[8];
    const float* b3    = (const float*)d_in[9];
    float* out = (float*)d_out;

    // ws layout (4B elems): norm_src[N] | norm_dst[N] | row_ptr[N+1] | csr_src[E]
    //                       | hs[N_PAD*D] | agg_h[N_PAD*D sh] | agg_l[N_PAD*D sh] | wt
    // gemm writes hs in place (agg fully consumed it before gemm runs).
    // Transients (deg_out, deg_in, cursor, bsums) alias the agg_h region:
    // last read by fill, before agg layer-1 writes agg_h.
    float* norm_src = (float*)d_ws;
    float* norm_dst = norm_src + N;
    int*   row_ptr  = (int*)(norm_dst + N);
    int*   csr_src  = row_ptr + (N + 1);
    float* hs       = (float*)(csr_src + E) + 3;  // 16B alignment
    short* agg_h    = (short*)(hs + (size_t)N_PAD * D);
    short* agg_l    = agg_h + (size_t)N_PAD * D;
    short* wt       = agg_l + (size_t)N_PAD * D;
    int*   deg_out  = (int*)agg_h;     // transient
    int*   deg_in   = deg_out + N;
    int*   cursor   = deg_in + N;
    int*   bsums    = cursor + N;

    hipMemsetAsync(deg_out, 0, 3 * (size_t)N * sizeof(int), stream);
    deg_kernel<<<(E + 255) / 256, 256, 0, stream>>>(src, dst, deg_out, deg_in);
    scan_bsum_norm_kernel<<<SCAN_NB, 256, 0, stream>>>(deg_out, deg_in,
                                                       norm_src, norm_dst, bsums);
    scan_bsums_kernel<<<1, 256, 0, stream>>>(bsums);
    scan_final_kernel<<<SCAN_NB, 256, 0, stream>>>(deg_in, bsums, row_ptr);
    fill_kernel<<<(E + 255) / 256, 256, 0, stream>>>(src, dst, row_ptr, cursor,
                                                     csr_src);
    gather_kernel<<<((size_t)N * 32 + 255) / 256, 256, 0, stream>>>(batch, emb,
                                                                    norm_src, hs);
    wprep_kernel<<<(3 * D * D + 255) / 256, 256, 0, stream>>>(W1, W2, W3, wt);

    const float* bs[3] = {b1, b2, b3};
    for (int l = 0; l < 3; ++l) {
        bool last = (l == 2);
        agg_kernel<<<((size_t)N * 64 + 255) / 256, 256, 0, stream>>>(
            row_ptr, csr_src, hs, agg_h, agg_l);
        gemm_mfma_kernel<<<GRID_M, 512, 0, stream>>>(
            agg_h, agg_l, wt + (size_t)l * 2 * D * D, bs[l], norm_dst,
            last ? nullptr : norm_src,
            last ? out : hs);
    }
}

// Round 14
// 378.077 us; speedup vs baseline: 1.0536x; 1.0056x over previous
//
#include <hip/hip_runtime.h>
#include <math.h>

typedef float f4 __attribute__((ext_vector_type(4)));
typedef float f32x4 __attribute__((ext_vector_type(4)));
typedef short s8 __attribute__((ext_vector_type(8)));  // 8 bf16 (4 VGPRs)
typedef short s4 __attribute__((ext_vector_type(4)));  // 4 bf16 (2 VGPRs)

static constexpr int N = 50000;
static constexpr int E = 800000;
static constexpr int D = 128;
static constexpr int SCAN_NB = (N + 255) / 256;        // 196
static constexpr int MBLK = 128;                       // gemm rows/block
static constexpr int GRID_M = (N + MBLK - 1) / MBLK;   // 391
static constexpr int N_PAD = GRID_M * MBLK;            // 50048
static constexpr int WT_PITCH = 136;                   // LDS pad

__device__ inline unsigned short f32_bf16_rne(float x) {
    unsigned u = __float_as_uint(x);
    return (unsigned short)((u + 0x7FFF + ((u >> 16) & 1)) >> 16);
}
__device__ inline float bf16_f32(unsigned short h) {
    return __uint_as_float((unsigned)h << 16);
}

// --- int degree histogram ---
__global__ void deg_kernel(const int* __restrict__ src, const int* __restrict__ dst,
                           int* __restrict__ deg_out, int* __restrict__ deg_in) {
    int e = blockIdx.x * 256 + threadIdx.x;
    if (e < E) {
        atomicAdd(&deg_out[src[e]], 1);
        atomicAdd(&deg_in[dst[e]], 1);
    }
}

// --- scan pass 1 (+ fused norms): per-block sums of deg_in ---
__global__ __launch_bounds__(256) void scan_bsum_norm_kernel(
    const int* __restrict__ deg_out, const int* __restrict__ deg_in,
    float* __restrict__ norm_src, float* __restrict__ norm_dst,
    int* __restrict__ bsums) {
    int i = blockIdx.x * 256 + threadIdx.x;
    int v = 0;
    if (i < N) {
        norm_src[i] = rsqrtf(fmaxf((float)deg_out[i], 1.0f));
        norm_dst[i] = rsqrtf(fmaxf((float)deg_in[i], 1.0f));
        v = deg_in[i];
    }
#pragma unroll
    for (int off = 1; off < 64; off <<= 1) v += __shfl_xor(v, off, 64);
    __shared__ int ws[4];
    if ((threadIdx.x & 63) == 0) ws[threadIdx.x >> 6] = v;
    __syncthreads();
    if (threadIdx.x == 0) bsums[blockIdx.x] = ws[0] + ws[1] + ws[2] + ws[3];
}

// --- scan pass 2 (folded pass): per-block base = sum(bsums[0..b)) computed
// in-block (196 ints, trivial), then rescan deg -> row_ptr ---
__global__ __launch_bounds__(256) void scan_final_kernel(const int* __restrict__ deg,
                                                         const int* __restrict__ bsums,
                                                         int* __restrict__ row_ptr) {
    __shared__ int s[256];
    __shared__ int base_s;
    int b = blockIdx.x, t = threadIdx.x;

    // block base: sum of bsums below b
    int bv = (t < b && t < SCAN_NB) ? bsums[t] : 0;
#pragma unroll
    for (int off = 1; off < 64; off <<= 1) bv += __shfl_xor(bv, off, 64);
    __shared__ int wsb[4];
    if ((t & 63) == 0) wsb[t >> 6] = bv;
    __syncthreads();
    if (t == 0) base_s = wsb[0] + wsb[1] + wsb[2] + wsb[3];

    int i = b * 256 + t;
    s[t] = (i < N) ? deg[i] : 0;
    __syncthreads();
    for (int off = 1; off < 256; off <<= 1) {
        int v = (t >= off) ? s[t - off] : 0;
        __syncthreads();
        s[t] += v;
        __syncthreads();
    }
    if (i < N) row_ptr[i + 1] = s[t] + base_s;
    if (i == 0) row_ptr[0] = 0;
}

// --- csr fill (ushort src ids: 50000 < 65536) ---
__global__ void fill_kernel(const int* __restrict__ src, const int* __restrict__ dst,
                            const int* __restrict__ row_ptr, int* __restrict__ cursor,
                            unsigned short* __restrict__ csr_src) {
    int e = blockIdx.x * 256 + threadIdx.x;
    if (e < E) {
        int d = dst[e];
        int pos = row_ptr[d] + atomicAdd(&cursor[d], 1);
        csr_src[pos] = (unsigned short)src[e];
    }
}

// --- hs[i] = emb[batch[i]] * norm_src[i] ---
__global__ void gather_kernel(const int* __restrict__ batch, const float* __restrict__ emb,
                              const float* __restrict__ norm_src, float* __restrict__ hs) {
    int gid = blockIdx.x * 256 + threadIdx.x;
    int i = gid >> 5;
    int c = (gid & 31) << 2;
    if (i < N) {
        float s = norm_src[i];
        f4 v = *(const f4*)(emb + (size_t)batch[i] * D + c);
        *(f4*)(hs + (size_t)i * D + c) = v * s;
    }
}

// --- agg: 1 wave/node, 2 edge-groups x 8-deep; full row; bf16 hi/lo out ---
// FETCH = compulsory 8 XCD x (25.6 MB table + 1.6 MB ushort csr).
__global__ void agg_kernel(const int* __restrict__ row_ptr,
                           const unsigned short* __restrict__ csr_src,
                           const float* __restrict__ hs,
                           short* __restrict__ agg_h, short* __restrict__ agg_l) {
    int gid = blockIdx.x * 256 + threadIdx.x;
    int node = gid >> 6;
    if (node >= N) return;
    int lane = threadIdx.x & 63;
    int grp = lane >> 5;
    int col = (lane & 31) << 2;
    int beg = row_ptr[node], end = row_ptr[node + 1];

    f4 a0 = (f4)0.0f, a1 = (f4)0.0f, a2 = (f4)0.0f, a3 = (f4)0.0f;
    f4 a4 = (f4)0.0f, a5 = (f4)0.0f, a6 = (f4)0.0f, a7 = (f4)0.0f;
    int e = beg + grp;
    for (; e + 14 < end; e += 16) {
        int s0 = csr_src[e];
        int s1 = csr_src[e + 2];
        int s2 = csr_src[e + 4];
        int s3 = csr_src[e + 6];
        int s4 = csr_src[e + 8];
        int s5 = csr_src[e + 10];
        int s6 = csr_src[e + 12];
        int s7 = csr_src[e + 14];
        a0 += *(const f4*)(hs + (size_t)s0 * D + col);
        a1 += *(const f4*)(hs + (size_t)s1 * D + col);
        a2 += *(const f4*)(hs + (size_t)s2 * D + col);
        a3 += *(const f4*)(hs + (size_t)s3 * D + col);
        a4 += *(const f4*)(hs + (size_t)s4 * D + col);
        a5 += *(const f4*)(hs + (size_t)s5 * D + col);
        a6 += *(const f4*)(hs + (size_t)s6 * D + col);
        a7 += *(const f4*)(hs + (size_t)s7 * D + col);
    }
    for (; e < end; e += 2)
        a0 += *(const f4*)(hs + (size_t)csr_src[e] * D + col);
    a0 += a1; a2 += a3; a4 += a5; a6 += a7;
    a0 += a2; a4 += a6;
    a0 += a4;

    f4 o;
#pragma unroll
    for (int j = 0; j < 4; ++j)
        o[j] = a0[j] + __shfl_xor(a0[j], 32, 64);
    if (grp == 0) {
        s4 oh, ol;
#pragma unroll
        for (int j = 0; j < 4; ++j) {
            unsigned short h = f32_bf16_rne(o[j]);
            oh[j] = (short)h;
            ol[j] = (short)f32_bf16_rne(o[j] - bf16_f32(h));
        }
        *(s4*)(agg_h + (size_t)node * D + col) = oh;
        *(s4*)(agg_l + (size_t)node * D + col) = ol;
    }
}

// --- W prep: wt[layer][hi/lo][n][k] = bf16 split of W[k][n] (transposed) ---
__global__ void wprep_kernel(const float* __restrict__ W1, const float* __restrict__ W2,
                             const float* __restrict__ W3, short* __restrict__ wt) {
    int idx = blockIdx.x * 256 + threadIdx.x;
    if (idx >= 3 * D * D) return;
    int l = idx >> 14;
    int e = idx & (D * D - 1);
    int n = e >> 7, k = e & 127;
    const float* W = (l == 0) ? W1 : ((l == 1) ? W2 : W3);
    float w = W[(size_t)k * D + n];
    unsigned short h = f32_bf16_rne(w);
    unsigned short lo = f32_bf16_rne(w - bf16_f32(h));
    wt[(size_t)l * 2 * D * D + (size_t)n * D + k] = (short)h;
    wt[(size_t)l * 2 * D * D + D * D + (size_t)n * D + k] = (short)lo;
}

// --- MFMA GEMM: 128 rows x 128 cols per block; 512 thr = 8 waves.
// grid=391 -> single occupancy round at 2 blk/CU. 3-term bf16 split.
__global__ __launch_bounds__(512, 2) void gemm_mfma_kernel(
    const short* __restrict__ Ah, const short* __restrict__ Al,
    const short* __restrict__ wth,
    const float* __restrict__ bias, const float* __restrict__ norm_dst,
    const float* __restrict__ post, float* __restrict__ out) {
    __shared__ short wt_h[D * WT_PITCH];   // 34816 B
    __shared__ short wt_l[D * WT_PITCH];   // 34816 B

    int tid = threadIdx.x;
    const short* gh = wth;
    const short* gl = wth + (size_t)D * D;

#pragma unroll
    for (int it = 0; it < 4; ++it) {
        int c = tid + it * 512;            // 2048 chunks of 8 shorts
        int n = c >> 4, kc = c & 15;
        *(s8*)(&wt_h[n * WT_PITCH + kc * 8]) = *(const s8*)(gh + (size_t)n * D + kc * 8);
        *(s8*)(&wt_l[n * WT_PITCH + kc * 8]) = *(const s8*)(gl + (size_t)n * D + kc * 8);
    }
    __syncthreads();

    int wv = tid >> 6;                     // 0..7
    int lane = tid & 63;
    int lg = lane >> 4;
    int lr = lane & 15;

    int arow = blockIdx.x * MBLK + wv * 16 + lr;
    const short* ahp = Ah + (size_t)arow * D;
    const short* alp = Al + (size_t)arow * D;

    f32x4 acc[8];
#pragma unroll
    for (int nt = 0; nt < 8; ++nt) acc[nt] = (f32x4)0.0f;

#pragma unroll
    for (int kt = 0; kt < 4; ++kt) {
        int ko = kt * 32 + lg * 8;
        s8 ah = *(const s8*)(ahp + ko);
        s8 al = *(const s8*)(alp + ko);
#pragma unroll
        for (int nt = 0; nt < 8; ++nt) {
            int bidx = (nt * 16 + lr) * WT_PITCH + ko;
            s8 bh = *(const s8*)(&wt_h[bidx]);
            s8 bl = *(const s8*)(&wt_l[bidx]);
            acc[nt] = __builtin_amdgcn_mfma_f32_16x16x32_bf16(ah, bh, acc[nt], 0, 0, 0);
            acc[nt] = __builtin_amdgcn_mfma_f32_16x16x32_bf16(al, bh, acc[nt], 0, 0, 0);
            acc[nt] = __builtin_amdgcn_mfma_f32_16x16x32_bf16(ah, bl, acc[nt], 0, 0, 0);
        }
    }

    int r0 = blockIdx.x * MBLK + wv * 16 + lg * 4;
    float nd[4], ps[4];
#pragma unroll
    for (int i = 0; i < 4; ++i) {
        int gr = r0 + i;
        nd[i] = (gr < N) ? norm_dst[gr] : 0.0f;
        ps[i] = (gr < N) ? (post ? post[gr] : 1.0f) : 0.0f;
    }
#pragma unroll
    for (int nt = 0; nt < 8; ++nt) {
        int col = nt * 16 + lr;
        float bv = bias[col];
#pragma unroll
        for (int i = 0; i < 4; ++i) {
            int gr = r0 + i;
            if (gr < N) {
                float v = fmaxf(acc[nt][i] * nd[i] + bv, 0.0f) * ps[i];
                out[(size_t)gr * D + col] = v;
            }
        }
    }
}

extern "C" void kernel_launch(void* const* d_in, const int* in_sizes, int n_in,
                              void* d_out, int out_size, void* d_ws, size_t ws_size,
                              hipStream_t stream) {
    const int*   batch = (const int*)d_in[0];
    const int*   src   = (const int*)d_in[1];
    const int*   dst   = (const int*)d_in[2];
    const float* emb   = (const float*)d_in[3];
    const float* W1    = (const float*)d_in[4];
    const float* b1    = (const float*)d_in[5];
    const float* W2    = (const float*)d_in[6];
    const float* b2    = (const float*)d_in[7];
    const float* W3    = (const float*)d_in[8];
    const float* b3    = (const float*)d_in[9];
    float* out = (float*)d_out;

    // ws layout (4B elems): norm_src[N] | norm_dst[N] | row_ptr[N+1] | csr_src[E ushort]
    //                       | hs[N_PAD*D] | agg_h[N_PAD*D sh] | agg_l[N_PAD*D sh] | wt
    // gemm writes hs in place (agg fully consumed it before gemm runs).
    // Transients (deg_out, deg_in, cursor, bsums) alias the agg_h region.
    float*          norm_src = (float*)d_ws;
    float*          norm_dst = norm_src + N;
    int*            row_ptr  = (int*)(norm_dst + N);
    unsigned short* csr_src  = (unsigned short*)(row_ptr + (N + 1));
    float*          hs       = (float*)(csr_src + E) + 2;  // 16B alignment
    short*          agg_h    = (short*)(hs + (size_t)N_PAD * D);
    short*          agg_l    = agg_h + (size_t)N_PAD * D;
    short*          wt       = agg_l + (size_t)N_PAD * D;
    int*            deg_out  = (int*)agg_h;     // transient
    int*            deg_in   = deg_out + N;
    int*            cursor   = deg_in + N;
    int*            bsums    = cursor + N;

    hipMemsetAsync(deg_out, 0, 3 * (size_t)N * sizeof(int), stream);
    deg_kernel<<<(E + 255) / 256, 256, 0, stream>>>(src, dst, deg_out, deg_in);
    scan_bsum_norm_kernel<<<SCAN_NB, 256, 0, stream>>>(deg_out, deg_in,
                                                       norm_src, norm_dst, bsums);
    scan_final_kernel<<<SCAN_NB, 256, 0, stream>>>(deg_in, bsums, row_ptr);
    fill_kernel<<<(E + 255) / 256, 256, 0, stream>>>(src, dst, row_ptr, cursor,
                                                     csr_src);
    gather_kernel<<<((size_t)N * 32 + 255) / 256, 256, 0, stream>>>(batch, emb,
                                                                    norm_src, hs);
    wprep_kernel<<<(3 * D * D + 255) / 256, 256, 0, stream>>>(W1, W2, W3, wt);

    const float* bs[3] = {b1, b2, b3};
    for (int l = 0; l < 3; ++l) {
        bool last = (l == 2);
        agg_kernel<<<((size_t)N * 64 + 255) / 256, 256, 0, stream>>>(
            row_ptr, csr_src, hs, agg_h, agg_l);
        gemm_mfma_kernel<<<GRID_M, 512, 0, stream>>>(
            agg_h, agg_l, wt + (size_t)l * 2 * D * D, bs[l], norm_dst,
            last ? nullptr : norm_src,
            last ? out : hs);
    }
}